// Round 1
// 799.990 us; speedup vs baseline: 1.0003x; 1.0003x over previous
//
#include <hip/hip_runtime.h>
#include <hip/hip_bf16.h>

// 3-step Euler residual block via bf16 MFMA implicit-GEMM.
//   t = relu(conv(x,w1)+b1); x += (1/3)*(conv(t,w2)+b2); x3 times; out = relu(x)
// B=16, C=128, H=W=128. Activations NHWC bf16 in ws (XB = x state, T = t).
// Conv as 9 tap-GEMMs split into 18 K=64 steps. Block = one (b,y) output row:
// 128 oc x 128 pix, 4 waves of 64x64.
//
// R3: async staging. global_load_lds width=16 for BOTH input-row and weight
// staging (linear LDS dest, XOR-chunk-swizzled per-lane global source so the
// stride-256B/128B ds_read_b128 patterns stay bank-minimal). Weights double-
// buffered per K=64 half-tap: step s computes from wbuf[s&1] while prefetching
// s+1 into wbuf[(s+1)&1], issued BEFORE the MFMA cluster; one barrier/step.
// Input row restaged synchronously only at ky boundaries (<=2 per block).
// XCD-chunked blockIdx swizzle: y-neighbors (sharing 2/3 input rows) on same L2.

#define BATCH 16
#define CH    128
#define HH    128
#define WW    128
#define H_STEP (1.0f/3.0f)

typedef short bf16x8 __attribute__((ext_vector_type(8)));
typedef float f32x4  __attribute__((ext_vector_type(4)));

__device__ __forceinline__ float bf2f(unsigned short u) {
    union { unsigned int i; float f; } c; c.i = ((unsigned int)u) << 16; return c.f;
}
__device__ __forceinline__ unsigned short f2bf(float f) {
    union { float f; unsigned int i; } c; c.f = f;
    unsigned int i = c.i;
    return (unsigned short)((i + 0x7FFFu + ((i >> 16) & 1u)) >> 16);  // RNE
}

// async 16B global->LDS. lptr must be wave-uniform; lane l lands at lptr+16*l.
__device__ __forceinline__ void gload16(const unsigned short* g, unsigned short* l) {
    __builtin_amdgcn_global_load_lds(
        (const __attribute__((address_space(1))) unsigned int*)g,
        (__attribute__((address_space(3))) unsigned int*)l, 16, 0, 0);
}

// ---------------- initial transpose: x0 NCHW fp32 -> XB NHWC bf16 --------------
__global__ __launch_bounds__(256)
void transpose_x(const float* __restrict__ x, unsigned short* __restrict__ xb)
{
    __shared__ unsigned short s[128 * 132];   // [ci][x], +4 pad
    const int tid = threadIdx.x;
    const int bz  = blockIdx.x;               // 0..2047 = (b,y)
    const int b = bz >> 7, y = bz & 127;

    #pragma unroll
    for (int it = 0; it < 16; ++it) {
        int idx = it * 256 + tid;             // 0..4095
        int ci = idx >> 5, xq = idx & 31;
        float4 v = *(const float4*)&x[(((size_t)b * CH + ci) * HH + y) * WW + xq * 4];
        uint2 p;
        p.x = (unsigned int)f2bf(v.x) | ((unsigned int)f2bf(v.y) << 16);
        p.y = (unsigned int)f2bf(v.z) | ((unsigned int)f2bf(v.w) << 16);
        *(uint2*)&s[ci * 132 + xq * 4] = p;
    }
    __syncthreads();
    #pragma unroll
    for (int it = 0; it < 8; ++it) {
        int idx = it * 256 + tid;             // 0..2047
        int xx = idx >> 4, cc = idx & 15;
        unsigned short t[8];
        #pragma unroll
        for (int k = 0; k < 8; ++k) t[k] = s[(cc * 8 + k) * 132 + xx];
        uint4 p;
        p.x = (unsigned int)t[0] | ((unsigned int)t[1] << 16);
        p.y = (unsigned int)t[2] | ((unsigned int)t[3] << 16);
        p.z = (unsigned int)t[4] | ((unsigned int)t[5] << 16);
        p.w = (unsigned int)t[6] | ((unsigned int)t[7] << 16);
        *(uint4*)&xb[((size_t)(b * HH + y) * WW + xx) * CH + cc * 8] = p;
    }
}

// --------------- weight convert: OIHW fp32 -> [tap][oc][ci] bf16 ---------------
__global__ __launch_bounds__(256)
void convert_w(const float* __restrict__ w, unsigned short* __restrict__ wb)
{
    int idx = blockIdx.x * 256 + threadIdx.x;   // 0..16383 = oc*128+ci
    #pragma unroll
    for (int t = 0; t < 9; ++t)
        wb[t * 16384 + idx] = f2bf(w[(size_t)idx * 9 + t]);
}

// ------------------------------ conv3x3 MFMA ----------------------------------
// MODE 0: outb = bf16(relu(acc + bias))                       (conv1 -> T)
// MODE 1: outb = bf16(res + h*(acc + bias))                   (conv2 -> XB, in place)
// MODE 2: outf = relu(res + h*(acc + bias)) fp32 NCHW         (final conv2 -> d_out)
template<int MODE>
__global__ __launch_bounds__(256, 2)
void conv_mfma(const unsigned short* __restrict__ in,   // NHWC bf16
               const unsigned short* __restrict__ wb,   // [9][128][128] bf16
               const float* __restrict__ bias,
               const unsigned short* resb,              // NHWC bf16 (may alias outb)
               unsigned short* outb,                    // NHWC bf16
               float* __restrict__ outf)                // NCHW fp32
{
    // Linear (unpadded) LDS; bank safety via XOR chunk swizzle baked into the
    // staging SOURCE address (gload_lds dest must be linear) and the read addr.
    // LDS slot (row, c) holds global 16B-chunk (c ^ (row&7)) of that row.
    __shared__ unsigned short s_in[130 * CH];        // rows 0/129 = zero halo, 33.3 KB
    __shared__ unsigned short s_w [2][128 * 64];     // K=64 half-tap dbuf, 2x16 KB

    const int tid = threadIdx.x;
    const int bz0 = blockIdx.x;
    const int bz  = ((bz0 & 7) << 8) | (bz0 >> 3);   // XCD-chunked swizzle (2048%8==0)
    const int b = bz >> 7, y = bz & 127;

    const int lane = tid & 63;
    const int wid  = tid >> 6;
    const int woc0 = (wid >> 1) * 64;
    const int wpx0 = (wid & 1) * 64;
    const int n16  = lane & 15;
    const int q    = lane >> 4;

    // per-lane staging decomposition
    const int wr   = lane >> 3;          // weights: row-within-call 0..7
    const int wc   = lane & 7;           //          chunk slot 0..7
    const int w_lane_elem = wr * CH + ((wc ^ wr) << 3);   // swizzled source offset
    const int xl   = lane >> 4;          // input: row-within-call 0..3
    const int ch16 = lane & 15;          //        chunk slot 0..15

    const int kylo = (y == 0)      ? 1 : 0;
    const int kyhi = (y == HH - 1) ? 1 : 2;
    const int NS   = (kyhi - kylo + 1) * 6;          // 6 K=64 steps per valid ky

    f32x4 acc[4][4];
    #pragma unroll
    for (int i = 0; i < 4; ++i)
        #pragma unroll
        for (int j = 0; j < 4; ++j) acc[i][j] = (f32x4)0.0f;

    // zero the x = -1 / x = 128 halo rows (swizzle irrelevant for zeros)
    if (tid < 32) {
        int r  = (tid < 16) ? 0 : 129;
        int cc = tid & 15;
        uint4 z = {0u, 0u, 0u, 0u};
        *(uint4*)&s_in[r * CH + cc * 8] = z;
    }

    // stage one input row (128 x-pos x 128 ci = 32 KB) into LDS rows 1..128
    auto stage_in = [&](int gy) {
        const size_t inrow = ((size_t)(b * HH + gy) * WW) * CH;
        #pragma unroll
        for (int c = 0; c < 8; ++c) {
            int x   = wid * 32 + c * 4 + xl;
            int swz = (x + 1) & 7;                       // LDS row = x+1
            const unsigned short* src = in + inrow + (size_t)x * CH + ((ch16 ^ swz) << 3);
            unsigned short* dst = (unsigned short*)s_in + CH + (wid * 8 + c) * 512;
            gload16(src, dst);
        }
    };
    // stage one K=64 half-tap of weights (128 oc x 64 ci = 16 KB)
    auto stage_w = [&](int tap, int kh, int buf) {
        const unsigned short* wt = wb + tap * 16384 + kh * 64;
        #pragma unroll
        for (int c = 0; c < 4; ++c) {
            int base_r = (wid * 4 + c) * 8;              // multiple of 8 -> swz = wr
            const unsigned short* src = wt + base_r * CH + w_lane_elem;
            unsigned short* dst = &s_w[buf][(wid * 4 + c) * 512];
            gload16(src, dst);
        }
    };

    // prologue: first input row + first weight half into buf 0
    stage_in(y + kylo - 1);
    stage_w(kylo * 3, 0, 0);
    __syncthreads();                                     // drains vmcnt(0)

    for (int s = 0; s < NS; ++s) {
        const int cur = s & 1;
        const int kyi = s / 6;
        const int r6  = s - kyi * 6;
        const int kx  = r6 >> 1;
        const int kh  = s & 1;                           // 6 is even -> parity == s&1

        // prefetch next step's weights into the other buffer (issued pre-MFMA;
        // L2 latency hides under this step's 32 MFMA + 16 ds_read)
        if (s + 1 < NS) {
            const int s1  = s + 1;
            const int ky1 = s1 / 6;
            const int r61 = s1 - ky1 * 6;
            stage_w((kylo + ky1) * 3 + (r61 >> 1), s1 & 1, cur ^ 1);
        }

        // K=64 compute from wbuf[cur] + s_in
        #pragma unroll
        for (int c0 = 0; c0 < 64; c0 += 32) {
            bf16x8 af[4], bfr[4];
            const int cqa = (c0 >> 3) + q;               // weight chunk 0..7
            #pragma unroll
            for (int i = 0; i < 4; ++i) {
                int row = woc0 + i * 16 + n16;
                af[i] = *(const bf16x8*)&s_w[cur][row * 64 + ((cqa ^ (row & 7)) << 3)];
            }
            const int cqb = kh * 8 + (c0 >> 3) + q;      // input chunk 0..15
            #pragma unroll
            for (int j = 0; j < 4; ++j) {
                int rowb = wpx0 + j * 16 + n16 + kx;     // pixel + kx - 1, +1 halo
                bfr[j] = *(const bf16x8*)&s_in[rowb * CH + ((cqb ^ (rowb & 7)) << 3)];
            }
            #pragma unroll
            for (int i = 0; i < 4; ++i)
                #pragma unroll
                for (int j = 0; j < 4; ++j)
                    acc[i][j] = __builtin_amdgcn_mfma_f32_16x16x32_bf16(
                        af[i], bfr[j], acc[i][j], 0, 0, 0);
        }

        if (r6 == 5 && s + 1 < NS) {
            // ky boundary: s_in is single-buffered -> must drain readers, then
            // restage synchronously (2x per block worst case; ~1k cyc exposed)
            __syncthreads();                             // also lands w-prefetch
            stage_in(y + (kylo + kyi + 1) - 1);
            __syncthreads();
        } else {
            __syncthreads();                             // vmcnt(0): prefetch landed
        }
    }

    // ------------------------------ epilogue ---------------------------------
    const int ybase = (b * HH + y) * WW;
    if (MODE == 0 || MODE == 1) {
        #pragma unroll
        for (int j = 0; j < 4; ++j) {
            int x = wpx0 + j * 16 + n16;
            size_t pbase = (size_t)(ybase + x) * CH;
            #pragma unroll
            for (int i = 0; i < 4; ++i) {
                int oc0 = woc0 + i * 16 + q * 4;
                float v0 = acc[i][j][0] + bias[oc0 + 0];
                float v1 = acc[i][j][1] + bias[oc0 + 1];
                float v2 = acc[i][j][2] + bias[oc0 + 2];
                float v3 = acc[i][j][3] + bias[oc0 + 3];
                if (MODE == 0) {
                    v0 = fmaxf(v0, 0.f); v1 = fmaxf(v1, 0.f);
                    v2 = fmaxf(v2, 0.f); v3 = fmaxf(v3, 0.f);
                } else {
                    uint2 rr = *(const uint2*)&resb[pbase + oc0];
                    v0 = bf2f((unsigned short)(rr.x & 0xffff)) + H_STEP * v0;
                    v1 = bf2f((unsigned short)(rr.x >> 16))    + H_STEP * v1;
                    v2 = bf2f((unsigned short)(rr.y & 0xffff)) + H_STEP * v2;
                    v3 = bf2f((unsigned short)(rr.y >> 16))    + H_STEP * v3;
                }
                uint2 po;
                po.x = (unsigned int)f2bf(v0) | ((unsigned int)f2bf(v1) << 16);
                po.y = (unsigned int)f2bf(v2) | ((unsigned int)f2bf(v3) << 16);
                *(uint2*)&outb[pbase + oc0] = po;
            }
        }
    } else {
        // fp32 NCHW out + final relu; residual still bf16 NHWC
        #pragma unroll
        for (int i = 0; i < 4; ++i) {
            #pragma unroll
            for (int r = 0; r < 4; ++r) {
                int oc = woc0 + i * 16 + q * 4 + r;
                float bv = bias[oc];
                size_t orow = ((size_t)(b * CH + oc) * HH + y) * WW;
                #pragma unroll
                for (int j = 0; j < 4; ++j) {
                    int x = wpx0 + j * 16 + n16;
                    float v = acc[i][j][r] + bv;
                    v = bf2f(resb[(size_t)(ybase + x) * CH + oc]) + H_STEP * v;
                    outf[orow + x] = fmaxf(v, 0.f);
                }
            }
        }
    }
}

// ------------------------------------------------------------------------------
extern "C" void kernel_launch(void* const* d_in, const int* in_sizes, int n_in,
                              void* d_out, int out_size, void* d_ws, size_t ws_size,
                              hipStream_t stream) {
    const float* x0 = (const float*)d_in[0];
    const float* w1 = (const float*)d_in[1];
    const float* b1 = (const float*)d_in[2];
    const float* w2 = (const float*)d_in[3];
    const float* b2 = (const float*)d_in[4];

    const size_t NELEM = (size_t)BATCH * CH * HH * WW;       // 33,554,432
    unsigned short* XB = (unsigned short*)d_ws;              // x state, NHWC bf16
    unsigned short* T  = XB + NELEM;                         // t,       NHWC bf16

    unsigned short* WB1;
    if (ws_size >= NELEM * 4 + 2 * 294912)
        WB1 = T + NELEM;
    else
        WB1 = (unsigned short*)d_in[0];                      // x0 dead after transpose
    unsigned short* WB2 = WB1 + 9 * 16384;

    dim3 block(256);
    dim3 gridRow(BATCH * HH);    // 2048: one block per (b, y)

    transpose_x<<<gridRow, block, 0, stream>>>(x0, XB);      // reads x0 first
    convert_w<<<dim3(64), block, 0, stream>>>(w1, WB1);      // then x0 may be clobbered
    convert_w<<<dim3(64), block, 0, stream>>>(w2, WB2);

    // step 1
    conv_mfma<0><<<gridRow, block, 0, stream>>>(XB, WB1, b1, nullptr, T, nullptr);
    conv_mfma<1><<<gridRow, block, 0, stream>>>(T, WB2, b2, XB, XB, nullptr);
    // step 2
    conv_mfma<0><<<gridRow, block, 0, stream>>>(XB, WB1, b1, nullptr, T, nullptr);
    conv_mfma<1><<<gridRow, block, 0, stream>>>(T, WB2, b2, XB, XB, nullptr);
    // step 3 (final relu, fp32 NCHW out)
    conv_mfma<0><<<gridRow, block, 0, stream>>>(XB, WB1, b1, nullptr, T, nullptr);
    conv_mfma<2><<<gridRow, block, 0, stream>>>(T, WB2, b2, XB, nullptr, (float*)d_out);
}

// Round 2
// 797.631 us; speedup vs baseline: 1.0032x; 1.0030x over previous
//
#include <hip/hip_runtime.h>
#include <hip/hip_bf16.h>

// 3-step Euler residual block via bf16 MFMA implicit-GEMM.
//   t = relu(conv(x,w1)+b1); x += (1/3)*(conv(t,w2)+b2); x3 times; out = relu(x)
// B=16, C=128, H=W=128. Activations NHWC bf16 in ws (XB = x state, T = t).
// Conv as 9 tap-GEMMs split into 36 K=32 steps. Block = one (b,y) output row:
// 128 oc x 128 pix, 4 waves of 64x64.
//
// R4: occupancy. R3's async staging halved HBM traffic (FETCH 136->69 MB) but
// dur was flat -> latency-bound at 2 blocks/CU (2 waves/SIMD), not BW-bound.
// Shrink weight dbuf to K=32 half-tiles (2x8 KB): LDS 66 -> 48.5 KB -> 3
// blocks/CU (3 waves/SIMD, m97-like occupancy). Same accumulation order
// (kq=0..3 == old c0 order) -> bit-identical numerics.

#define BATCH 16
#define CH    128
#define HH    128
#define WW    128
#define H_STEP (1.0f/3.0f)

typedef short bf16x8 __attribute__((ext_vector_type(8)));
typedef float f32x4  __attribute__((ext_vector_type(4)));

__device__ __forceinline__ float bf2f(unsigned short u) {
    union { unsigned int i; float f; } c; c.i = ((unsigned int)u) << 16; return c.f;
}
__device__ __forceinline__ unsigned short f2bf(float f) {
    union { float f; unsigned int i; } c; c.f = f;
    unsigned int i = c.i;
    return (unsigned short)((i + 0x7FFFu + ((i >> 16) & 1u)) >> 16);  // RNE
}

// async 16B global->LDS. lptr must be wave-uniform; lane l lands at lptr+16*l.
__device__ __forceinline__ void gload16(const unsigned short* g, unsigned short* l) {
    __builtin_amdgcn_global_load_lds(
        (const __attribute__((address_space(1))) unsigned int*)g,
        (__attribute__((address_space(3))) unsigned int*)l, 16, 0, 0);
}

// ---------------- initial transpose: x0 NCHW fp32 -> XB NHWC bf16 --------------
__global__ __launch_bounds__(256)
void transpose_x(const float* __restrict__ x, unsigned short* __restrict__ xb)
{
    __shared__ unsigned short s[128 * 132];   // [ci][x], +4 pad
    const int tid = threadIdx.x;
    const int bz  = blockIdx.x;               // 0..2047 = (b,y)
    const int b = bz >> 7, y = bz & 127;

    #pragma unroll
    for (int it = 0; it < 16; ++it) {
        int idx = it * 256 + tid;             // 0..4095
        int ci = idx >> 5, xq = idx & 31;
        float4 v = *(const float4*)&x[(((size_t)b * CH + ci) * HH + y) * WW + xq * 4];
        uint2 p;
        p.x = (unsigned int)f2bf(v.x) | ((unsigned int)f2bf(v.y) << 16);
        p.y = (unsigned int)f2bf(v.z) | ((unsigned int)f2bf(v.w) << 16);
        *(uint2*)&s[ci * 132 + xq * 4] = p;
    }
    __syncthreads();
    #pragma unroll
    for (int it = 0; it < 8; ++it) {
        int idx = it * 256 + tid;             // 0..2047
        int xx = idx >> 4, cc = idx & 15;
        unsigned short t[8];
        #pragma unroll
        for (int k = 0; k < 8; ++k) t[k] = s[(cc * 8 + k) * 132 + xx];
        uint4 p;
        p.x = (unsigned int)t[0] | ((unsigned int)t[1] << 16);
        p.y = (unsigned int)t[2] | ((unsigned int)t[3] << 16);
        p.z = (unsigned int)t[4] | ((unsigned int)t[5] << 16);
        p.w = (unsigned int)t[6] | ((unsigned int)t[7] << 16);
        *(uint4*)&xb[((size_t)(b * HH + y) * WW + xx) * CH + cc * 8] = p;
    }
}

// --------------- weight convert: OIHW fp32 -> [tap][oc][ci] bf16 ---------------
__global__ __launch_bounds__(256)
void convert_w(const float* __restrict__ w, unsigned short* __restrict__ wb)
{
    int idx = blockIdx.x * 256 + threadIdx.x;   // 0..16383 = oc*128+ci
    #pragma unroll
    for (int t = 0; t < 9; ++t)
        wb[t * 16384 + idx] = f2bf(w[(size_t)idx * 9 + t]);
}

// ------------------------------ conv3x3 MFMA ----------------------------------
// MODE 0: outb = bf16(relu(acc + bias))                       (conv1 -> T)
// MODE 1: outb = bf16(res + h*(acc + bias))                   (conv2 -> XB, in place)
// MODE 2: outf = relu(res + h*(acc + bias)) fp32 NCHW         (final conv2 -> d_out)
template<int MODE>
__global__ __launch_bounds__(256, 3)
void conv_mfma(const unsigned short* __restrict__ in,   // NHWC bf16
               const unsigned short* __restrict__ wb,   // [9][128][128] bf16
               const float* __restrict__ bias,
               const unsigned short* resb,              // NHWC bf16 (may alias outb)
               unsigned short* outb,                    // NHWC bf16
               float* __restrict__ outf)                // NCHW fp32
{
    // Linear (unpadded) LDS; bank safety via XOR chunk swizzle baked into the
    // staging SOURCE address (gload_lds dest must be linear) and the read addr.
    // s_in: slot (row, c) holds global 16B-chunk (c ^ (row&7)) of that row.
    // s_w : slot (row, c) holds k-chunk (c ^ (row&3)) of that row (4 chunks/row).
    __shared__ unsigned short s_in[130 * CH];        // rows 0/129 = zero halo, 32.5 KB
    __shared__ unsigned short s_w [2][128 * 32];     // K=32 quarter-tap dbuf, 2x8 KB

    const int tid = threadIdx.x;
    const int bz0 = blockIdx.x;
    const int bz  = ((bz0 & 7) << 8) | (bz0 >> 3);   // XCD-chunked swizzle (2048%8==0)
    const int b = bz >> 7, y = bz & 127;

    const int lane = tid & 63;
    const int wid  = tid >> 6;
    const int woc0 = (wid >> 1) * 64;
    const int wpx0 = (wid & 1) * 64;
    const int n16  = lane & 15;
    const int q    = lane >> 4;

    // per-lane staging decomposition
    const int wrow4 = lane >> 2;         // weights: row-within-call 0..15
    const int wslot = lane & 3;          //          16B k-chunk slot 0..3
    const int xl    = lane >> 4;         // input: x-within-group 0..3
    const int ch16  = lane & 15;         //        chunk slot 0..15

    const int kylo = (y == 0)      ? 1 : 0;
    const int kyhi = (y == HH - 1) ? 1 : 2;
    const int NS   = (kyhi - kylo + 1) * 12;         // 12 K=32 steps per valid ky

    f32x4 acc[4][4];
    #pragma unroll
    for (int i = 0; i < 4; ++i)
        #pragma unroll
        for (int j = 0; j < 4; ++j) acc[i][j] = (f32x4)0.0f;

    // zero the x = -1 / x = 128 halo rows (swizzle irrelevant for zeros)
    if (tid < 32) {
        int r  = (tid < 16) ? 0 : 129;
        int cc = tid & 15;
        uint4 z = {0u, 0u, 0u, 0u};
        *(uint4*)&s_in[r * CH + cc * 8] = z;
    }

    // stage one input row (128 x-pos x 128 ci = 32 KB) into LDS rows 1..128
    auto stage_in = [&](int gy) {
        const size_t inrow = ((size_t)(b * HH + gy) * WW) * CH;
        #pragma unroll
        for (int c = 0; c < 8; ++c) {
            int x   = wid * 32 + c * 4 + xl;
            int swz = (x + 1) & 7;                       // LDS row = x+1
            const unsigned short* src = in + inrow + (size_t)x * CH + ((ch16 ^ swz) << 3);
            unsigned short* dst = (unsigned short*)s_in + CH + (wid * 8 + c) * 512;
            gload16(src, dst);
        }
    };
    // stage one K=32 quarter-tap of weights (128 oc x 32 ci = 8 KB)
    auto stage_w = [&](int tap, int kq, int buf) {
        const unsigned short* wt = wb + tap * 16384 + kq * 32;
        #pragma unroll
        for (int c = 0; c < 2; ++c) {
            int row = (wid * 2 + c) * 16 + wrow4;        // oc row 0..127
            const unsigned short* src = wt + row * 128 + ((wslot ^ (row & 3)) << 3);
            unsigned short* dst = &s_w[buf][(wid * 2 + c) * 512];
            gload16(src, dst);
        }
    };

    // prologue: first input row + first weight quarter into buf 0
    stage_in(y + kylo - 1);
    stage_w(kylo * 3, 0, 0);
    __syncthreads();                                     // drains vmcnt(0)

    int kyi = 0, r12 = 0;
    for (int s = 0; s < NS; ++s) {
        const int cur = s & 1;                           // 12 even -> clean parity
        const int kx  = r12 >> 2;
        const int kq  = r12 & 3;

        // next step coords (scalar, no divide)
        int r12n = r12 + 1, kyin = kyi;
        if (r12n == 12) { r12n = 0; ++kyin; }

        // prefetch next step's weights into the other buffer (issued pre-MFMA;
        // L2 latency hides under this step's 16 MFMA + other blocks' work)
        if (s + 1 < NS)
            stage_w((kylo + kyin) * 3 + (r12n >> 2), r12n & 3, cur ^ 1);

        // K=32 compute from wbuf[cur] + s_in
        {
            bf16x8 af[4], bfr[4];
            #pragma unroll
            for (int i = 0; i < 4; ++i) {
                int row = woc0 + i * 16 + n16;
                af[i] = *(const bf16x8*)&s_w[cur][row * 32 + ((q ^ (row & 3)) << 3)];
            }
            const int cqb = kq * 4 + q;                  // input chunk 0..15
            #pragma unroll
            for (int j = 0; j < 4; ++j) {
                int rowb = wpx0 + j * 16 + n16 + kx;     // pixel + kx - 1, +1 halo
                bfr[j] = *(const bf16x8*)&s_in[rowb * CH + ((cqb ^ (rowb & 7)) << 3)];
            }
            #pragma unroll
            for (int i = 0; i < 4; ++i)
                #pragma unroll
                for (int j = 0; j < 4; ++j)
                    acc[i][j] = __builtin_amdgcn_mfma_f32_16x16x32_bf16(
                        af[i], bfr[j], acc[i][j], 0, 0, 0);
        }

        if (r12 == 11 && s + 1 < NS) {
            // ky boundary: s_in is single-buffered -> drain readers, restage
            __syncthreads();                             // also lands w-prefetch
            stage_in(y + kylo + kyi);                    // next gy = y+(kylo+kyi+1)-1
            __syncthreads();
        } else {
            __syncthreads();                             // vmcnt(0): prefetch landed
        }
        r12 = r12n; kyi = kyin;
    }

    // ------------------------------ epilogue ---------------------------------
    const int ybase = (b * HH + y) * WW;
    if (MODE == 0 || MODE == 1) {
        #pragma unroll
        for (int j = 0; j < 4; ++j) {
            int x = wpx0 + j * 16 + n16;
            size_t pbase = (size_t)(ybase + x) * CH;
            #pragma unroll
            for (int i = 0; i < 4; ++i) {
                int oc0 = woc0 + i * 16 + q * 4;
                float v0 = acc[i][j][0] + bias[oc0 + 0];
                float v1 = acc[i][j][1] + bias[oc0 + 1];
                float v2 = acc[i][j][2] + bias[oc0 + 2];
                float v3 = acc[i][j][3] + bias[oc0 + 3];
                if (MODE == 0) {
                    v0 = fmaxf(v0, 0.f); v1 = fmaxf(v1, 0.f);
                    v2 = fmaxf(v2, 0.f); v3 = fmaxf(v3, 0.f);
                } else {
                    uint2 rr = *(const uint2*)&resb[pbase + oc0];
                    v0 = bf2f((unsigned short)(rr.x & 0xffff)) + H_STEP * v0;
                    v1 = bf2f((unsigned short)(rr.x >> 16))    + H_STEP * v1;
                    v2 = bf2f((unsigned short)(rr.y & 0xffff)) + H_STEP * v2;
                    v3 = bf2f((unsigned short)(rr.y >> 16))    + H_STEP * v3;
                }
                uint2 po;
                po.x = (unsigned int)f2bf(v0) | ((unsigned int)f2bf(v1) << 16);
                po.y = (unsigned int)f2bf(v2) | ((unsigned int)f2bf(v3) << 16);
                *(uint2*)&outb[pbase + oc0] = po;
            }
        }
    } else {
        // fp32 NCHW out + final relu; residual still bf16 NHWC
        #pragma unroll
        for (int i = 0; i < 4; ++i) {
            #pragma unroll
            for (int r = 0; r < 4; ++r) {
                int oc = woc0 + i * 16 + q * 4 + r;
                float bv = bias[oc];
                size_t orow = ((size_t)(b * CH + oc) * HH + y) * WW;
                #pragma unroll
                for (int j = 0; j < 4; ++j) {
                    int x = wpx0 + j * 16 + n16;
                    float v = acc[i][j][r] + bv;
                    v = bf2f(resb[(size_t)(ybase + x) * CH + oc]) + H_STEP * v;
                    outf[orow + x] = fmaxf(v, 0.f);
                }
            }
        }
    }
}

// ------------------------------------------------------------------------------
extern "C" void kernel_launch(void* const* d_in, const int* in_sizes, int n_in,
                              void* d_out, int out_size, void* d_ws, size_t ws_size,
                              hipStream_t stream) {
    const float* x0 = (const float*)d_in[0];
    const float* w1 = (const float*)d_in[1];
    const float* b1 = (const float*)d_in[2];
    const float* w2 = (const float*)d_in[3];
    const float* b2 = (const float*)d_in[4];

    const size_t NELEM = (size_t)BATCH * CH * HH * WW;       // 33,554,432
    unsigned short* XB = (unsigned short*)d_ws;              // x state, NHWC bf16
    unsigned short* T  = XB + NELEM;                         // t,       NHWC bf16

    unsigned short* WB1;
    if (ws_size >= NELEM * 4 + 2 * 294912)
        WB1 = T + NELEM;
    else
        WB1 = (unsigned short*)d_in[0];                      // x0 dead after transpose
    unsigned short* WB2 = WB1 + 9 * 16384;

    dim3 block(256);
    dim3 gridRow(BATCH * HH);    // 2048: one block per (b, y)

    transpose_x<<<gridRow, block, 0, stream>>>(x0, XB);      // reads x0 first
    convert_w<<<dim3(64), block, 0, stream>>>(w1, WB1);      // then x0 may be clobbered
    convert_w<<<dim3(64), block, 0, stream>>>(w2, WB2);

    // step 1
    conv_mfma<0><<<gridRow, block, 0, stream>>>(XB, WB1, b1, nullptr, T, nullptr);
    conv_mfma<1><<<gridRow, block, 0, stream>>>(T, WB2, b2, XB, XB, nullptr);
    // step 2
    conv_mfma<0><<<gridRow, block, 0, stream>>>(XB, WB1, b1, nullptr, T, nullptr);
    conv_mfma<1><<<gridRow, block, 0, stream>>>(T, WB2, b2, XB, XB, nullptr);
    // step 3 (final relu, fp32 NCHW out)
    conv_mfma<0><<<gridRow, block, 0, stream>>>(XB, WB1, b1, nullptr, T, nullptr);
    conv_mfma<2><<<gridRow, block, 0, stream>>>(T, WB2, b2, XB, nullptr, (float*)d_out);
}